// Round 27
// baseline (82.316 us; speedup 1.0000x reference)
//
#include <hip/hip_runtime.h>
#include <hip/hip_bf16.h>
#include <stdint.h>

#define DD 256
#define NB 16
#define NN 1024
#define MTOT (NB * NN)  // 16384

typedef __attribute__((ext_vector_type(8))) short short8;
typedef __attribute__((ext_vector_type(4))) float f32x4;

__device__ __forceinline__ ushort f2b(float f) {
  uint32_t u = __float_as_uint(f);
  return (ushort)((u + 0x7fffu + ((u >> 16) & 1u)) >> 16);
}

// ---------------------------------------------------------------------------
// Preconvert the three 256x256 fp32 weight matrices to bf16 (row-major).
__global__ __launch_bounds__(256) void wconv(const float* __restrict__ W_w,
                                             const float* __restrict__ Q_w,
                                             const float* __restrict__ K_w,
                                             ushort* __restrict__ wbf) {
  int idx4 = blockIdx.x * blockDim.x + threadIdx.x;  // [0, 49152)
  int m = idx4 >> 14;          // matrix index 0..2
  int off = idx4 & 16383;      // float4 index within matrix
  const float* src = (m == 0) ? W_w : (m == 1) ? Q_w : K_w;
  float4 v = ((const float4*)src)[off];
  ushort4 b4;
  b4.x = f2b(v.x); b4.y = f2b(v.y); b4.z = f2b(v.z); b4.w = f2b(v.w);
  ((ushort4*)(wbf + m * 65536))[off] = b4;
}

// Stage a preconverted 256x256 bf16 weight matrix into LDS, XOR-swizzled.
__device__ __forceinline__ void stage_wbf(const ushort* __restrict__ Wb,
                                          ushort* Wl, int tid) {
#pragma unroll
  for (int i = 0; i < 32; ++i) {
    int idx8 = i * 256 + tid;        // uint4 index (8 bf16)
    int row = idx8 >> 5;             // 32 uint4 per 256-elem row
    int col0 = (idx8 & 31) << 3;     // element col
    uint4 v = ((const uint4*)Wb)[idx8];
    int byte = (row * 512 + col0 * 2) ^ ((row & 7) << 4);
    *(uint4*)((char*)Wl + byte) = v;
  }
}

// ---------------------------------------------------------------------------
// Fused h/q/k GEMM (round-25, unchanged).
__global__ __launch_bounds__(256, 1) void gemm_fused(
    const float* __restrict__ feature, const ushort* __restrict__ wbf,
    const float* __restrict__ W_b, const float* __restrict__ Q_b,
    const float* __restrict__ K_b, ushort* __restrict__ hT,
    ushort* __restrict__ q, ushort* __restrict__ k) {
  __shared__ ushort Wl[256 * 256];  // 128 KB; doubles as Tl transpose buffer
  const int tid = threadIdx.x;
  const int w = tid >> 6, lane = tid & 63, l15 = lane & 15, hi = lane >> 4;
  const int m0 = blockIdx.x * 64 + w * 16;
  const int arow = m0 + l15;

  // ---- h = feature @ W_w^T + W_b ----
  stage_wbf(wbf, Wl, tid);
  __syncthreads();

  f32x4 acc[16] = {};
#pragma unroll
  for (int kk = 0; kk < 8; ++kk) {
    const int k0 = kk * 32 + hi * 8;
    const float4* ap = (const float4*)(feature + arow * 256 + k0);
    float4 x = ap[0], y = ap[1];
    short8 a;
    a[0] = (short)f2b(x.x); a[1] = (short)f2b(x.y);
    a[2] = (short)f2b(x.z); a[3] = (short)f2b(x.w);
    a[4] = (short)f2b(y.x); a[5] = (short)f2b(y.y);
    a[6] = (short)f2b(y.z); a[7] = (short)f2b(y.w);
#pragma unroll
    for (int et = 0; et < 16; ++et) {
      int er = et * 16 + l15;
      short8 bf = *(const short8*)((const char*)Wl +
                                   ((er * 512 + k0 * 2) ^ ((er & 7) << 4)));
      acc[et] = __builtin_amdgcn_mfma_f32_16x16x32_bf16(a, bf, acc[et], 0, 0, 0);
    }
  }

  ushort hvals[16][4];
#pragma unroll
  for (int et = 0; et < 16; ++et) {
    float bv = W_b[et * 16 + l15];
#pragma unroll
    for (int r = 0; r < 4; ++r) hvals[et][r] = f2b(acc[et][r] + bv);
  }

  // ---- transpose h into Tl(=Wl) [256][64] ----
  __syncthreads();  // all waves done reading Wl
  ushort* Tl = Wl;
  {
    const int mloc = w * 16 + hi * 4;
#pragma unroll
    for (int et = 0; et < 16; ++et)
#pragma unroll
      for (int r = 0; r < 4; ++r)
        Tl[(et * 16 + l15) * 64 + mloc + r] = hvals[et][r];
  }
  __syncthreads();

  // ---- (a) h A-frags back to registers; (b) hT to global ----
  short8 qa[8];
#pragma unroll
  for (int kk = 0; kk < 8; ++kk) {
    const int k0 = kk * 32 + hi * 8;
#pragma unroll
    for (int j = 0; j < 8; ++j)
      qa[kk][j] = (short)Tl[(k0 + j) * 64 + w * 16 + l15];
  }
  {
    const int bidx = blockIdx.x >> 4;
    const int n0 = (blockIdx.x & 15) * 64;
    ushort* dst = hT + bidx * (256 * 1024) + tid * 1024 + n0;
    const uint4* src = (const uint4*)(Tl + tid * 64);
#pragma unroll
    for (int j = 0; j < 8; ++j) ((uint4*)dst)[j] = src[j];
  }
  __syncthreads();  // Tl reads done before Q_w staging overwrites

  // ---- q = h @ Q_w^T + Q_b ----
  stage_wbf(wbf + 65536, Wl, tid);
  __syncthreads();
#pragma unroll
  for (int et = 0; et < 16; ++et) acc[et] = (f32x4){0.f, 0.f, 0.f, 0.f};
#pragma unroll
  for (int kk = 0; kk < 8; ++kk) {
    const int k0 = kk * 32 + hi * 8;
#pragma unroll
    for (int et = 0; et < 16; ++et) {
      int er = et * 16 + l15;
      short8 bf = *(const short8*)((const char*)Wl +
                                   ((er * 512 + k0 * 2) ^ ((er & 7) << 4)));
      acc[et] = __builtin_amdgcn_mfma_f32_16x16x32_bf16(qa[kk], bf, acc[et], 0, 0, 0);
    }
  }
#pragma unroll
  for (int et = 0; et < 16; ++et) {
    int e = et * 16 + l15;
    float bv = Q_b[e];
#pragma unroll
    for (int r = 0; r < 4; ++r)
      q[(m0 + hi * 4 + r) * 256 + e] = f2b(acc[et][r] + bv);
  }
  __syncthreads();  // q-compute reads of Wl done before K_w staging

  // ---- k = h @ K_w^T + K_b ----
  stage_wbf(wbf + 131072, Wl, tid);
  __syncthreads();
#pragma unroll
  for (int et = 0; et < 16; ++et) acc[et] = (f32x4){0.f, 0.f, 0.f, 0.f};
#pragma unroll
  for (int kk = 0; kk < 8; ++kk) {
    const int k0 = kk * 32 + hi * 8;
#pragma unroll
    for (int et = 0; et < 16; ++et) {
      int er = et * 16 + l15;
      short8 bf = *(const short8*)((const char*)Wl +
                                   ((er * 512 + k0 * 2) ^ ((er & 7) << 4)));
      acc[et] = __builtin_amdgcn_mfma_f32_16x16x32_bf16(qa[kk], bf, acc[et], 0, 0, 0);
    }
  }
#pragma unroll
  for (int et = 0; et < 16; ++et) {
    int e = et * 16 + l15;
    float bv = K_b[e];
#pragma unroll
    for (int r = 0; r < 4; ++r)
      k[(m0 + hi * 4 + r) * 256 + e] = f2b(acc[et][r] + bv);
  }
}

// ---------------------------------------------------------------------------
// Fused attention: r24/r25 double-buffered single-barrier structure + T14
// issue-early staging FORCED via inline-asm global_load_dwordx4 (r26's C-level
// version was sunk by the compiler: VGPR stayed 116). asm volatile loads keep
// their issue point; explicit s_waitcnt vmcnt(0) + sched_barrier(0) fences
// the ds_writes (guide rule #18).
#define SM_KT0 0       // ushort [64*256]  32768 B
#define SM_KT1 32768   // ushort [64*256]  32768 B
#define SM_HT0 65536   // ushort [256*64]  32768 B
#define SM_HT1 98304   // ushort [256*64]  32768 B
#define SM_PL 131072   // ushort Pl[8*16*32]  8192 B
#define SM_M2 139264   // uint   M2[2][128]   1024 B
#define SM_CM 140288   // float  Cm[64]        256 B
#define SM_SZ 140544

// P-buffer swizzle: XOR in bits>=4 keeps 16B blocks intact for ds_read_b128.
__device__ __forceinline__ int pswz(int row, int bytecol) {
  return (row * 64 + bytecol) ^ ((row & 7) << 4) ^ ((row >> 3) << 5);
}

__global__ __launch_bounds__(512, 2) void attn8(
    const ushort* __restrict__ Q, const ushort* __restrict__ Kb,
    const ushort* __restrict__ HT, const int* __restrict__ graph,
    float* __restrict__ out) {
  __shared__ __align__(16) char smem[SM_SZ];
  ushort* Pl = (ushort*)(smem + SM_PL);
  uint* M2 = (uint*)(smem + SM_M2);
  float* Cm = (float*)(smem + SM_CM);

  const int tid = threadIdx.x;
  const int w = tid >> 6, lane = tid & 63, l15 = lane & 15, hi = lane >> 4;
  const int wg = w >> 1, half = w & 1;
  // XCD-aware remap: XCD x handles batches {2x, 2x+1}
  const int hw = blockIdx.x;
  const int slot = hw >> 3;
  const int b = (hw & 7) * 2 + (slot >> 4);
  const int q0 = (slot & 15) * 64;
  const int qrow_a = q0 + wg * 16 + l15;
  const int qrow_cl = wg * 16 + hi * 4;  // local row base (+r)
  const int* grow_base = graph + (b * 1024 + q0 + w * 8) * 1024 + lane;

  int greg[8];
  uint4 kreg[4], hreg[4];

  // issue tile tt's K/H^T loads via asm (not sinkable by the compiler)
#define STAGE_ISSUE(tt)                                                       \
  {                                                                           \
    _Pragma("unroll") for (int i = 0; i < 4; ++i) {                           \
      int c = i * 512 + tid;                                                  \
      int krow = c >> 5, col0 = (c & 31) << 3;                                \
      const uint4* kp =                                                       \
          (const uint4*)(Kb + (b * 1024 + (tt) * 64 + krow) * 256 + col0);    \
      asm volatile("global_load_dwordx4 %0, %1, off"                          \
                   : "=&v"(kreg[i])                                           \
                   : "v"(kp));                                                \
    }                                                                         \
    _Pragma("unroll") for (int i = 0; i < 4; ++i) {                           \
      int c = i * 512 + tid;                                                  \
      int drow = c >> 3, col0 = (c & 7) << 3;                                 \
      const uint4* hp = (const uint4*)(HT + b * (256 * 1024) + drow * 1024 +  \
                                       (tt) * 64 + col0);                     \
      asm volatile("global_load_dwordx4 %0, %1, off"                          \
                   : "=&v"(hreg[i])                                           \
                   : "v"(hp));                                                \
    }                                                                         \
  }

  // drain asm loads, then land registers into buffer pair bb (r10 layout)
#define STAGE_WRITE(bb)                                                       \
  {                                                                           \
    asm volatile("s_waitcnt vmcnt(0)" ::: "memory");                          \
    __builtin_amdgcn_sched_barrier(0);                                        \
    ushort* Kd = (ushort*)(smem + ((bb) ? SM_KT1 : SM_KT0));                  \
    ushort* Hd = (ushort*)(smem + ((bb) ? SM_HT1 : SM_HT0));                  \
    _Pragma("unroll") for (int i = 0; i < 4; ++i) {                           \
      int c = i * 512 + tid;                                                  \
      int krow = c >> 5, col0 = (c & 31) << 3;                                \
      *(uint4*)((char*)Kd + ((krow * 512 + col0 * 2) ^ ((krow & 7) << 4))) =  \
          kreg[i];                                                            \
    }                                                                         \
    _Pragma("unroll") for (int i = 0; i < 4; ++i) {                           \
      int c = i * 512 + tid;                                                  \
      int drow = c >> 3, col0 = (c & 7) << 3;                                 \
      *(uint4*)((char*)Hd + ((drow * 128 + col0 * 2) ^ ((drow & 7) << 4))) =  \
          hreg[i];                                                            \
    }                                                                         \
  }

  // ---- prologue: stage tile 0 into buf0; graph(0) ballot into M2[0] ----
#pragma unroll
  for (int j = 0; j < 8; ++j) greg[j] = grow_base[j * 1024];

  STAGE_ISSUE(0);

  short8 qf[8];
#pragma unroll
  for (int kk = 0; kk < 8; ++kk)
    qf[kk] = *(const short8*)(Q + (b * 1024 + qrow_a) * 256 + kk * 32 + hi * 8);

  STAGE_WRITE(0);

#pragma unroll
  for (int j = 0; j < 8; ++j) {
    unsigned long long mm = __ballot(greg[j] != 0);
    if (lane == 0) {
      M2[(w * 8 + j) * 2] = (uint)mm;
      M2[(w * 8 + j) * 2 + 1] = (uint)(mm >> 32);
    }
  }

  float lR[4] = {0.f, 0.f, 0.f, 0.f};  // per-LANE partial row sums
  f32x4 o[16] = {};

  __syncthreads();  // tile 0 staged

  for (int t = 0; t < 16; ++t) {
    const int cur = t & 1;
    const ushort* Kt = (const ushort*)(smem + (cur ? SM_KT1 : SM_KT0));
    const ushort* Ht = (const ushort*)(smem + (cur ? SM_HT1 : SM_HT0));
    const uint* M2c = M2 + cur * 128;
    uint* M2n = M2 + (cur ^ 1) * 128;

    // issue next tile's loads NOW (asm: stays here); compute covers latency
    if (t < 15) {
      STAGE_ISSUE(t + 1);
#pragma unroll
      for (int j = 0; j < 8; ++j) greg[j] = grow_base[j * 1024 + (t + 1) * 64];
    }

    // S = q @ k^T : 16 rows x 32 keys (this wave's half)
    f32x4 s[2] = {};
    __builtin_amdgcn_s_setprio(1);
#pragma unroll
    for (int kk = 0; kk < 8; ++kk) {
#pragma unroll
      for (int nt = 0; nt < 2; ++nt) {
        int krow = half * 32 + nt * 16 + l15;
        short8 kf = *(const short8*)((const char*)Kt +
            ((krow * 512 + (kk * 32 + hi * 8) * 2) ^ ((krow & 7) << 4)));
        s[nt] = __builtin_amdgcn_mfma_f32_16x16x32_bf16(qf[kk], kf, s[nt], 0, 0, 0);
      }
    }
    __builtin_amdgcn_s_setprio(0);

    // scale, leaky, mask, exp — per-lane VALU only
    float p[2][4];
#pragma unroll
    for (int r = 0; r < 4; ++r) {
      uint mw = M2c[(qrow_cl + r) * 2 + half];
      float v0 = s[0][r] * 0.0625f; v0 = (v0 >= 0.f) ? v0 : 0.2f * v0;
      float v1 = s[1][r] * 0.0625f; v1 = (v1 >= 0.f) ? v1 : 0.2f * v1;
      float p0 = ((mw >> l15) & 1u) ? __expf(v0) : 0.f;
      float p1 = ((mw >> (16 + l15)) & 1u) ? __expf(v1) : 0.f;
      p[0][r] = p0; p[1][r] = p1;
      lR[r] += p0 + p1;
    }

    // P (C-layout) -> per-wave LDS -> A-frag layout
    ushort* Pw = Pl + w * 512;
#pragma unroll
    for (int nt = 0; nt < 2; ++nt)
#pragma unroll
      for (int r = 0; r < 4; ++r) {
        int row = hi * 4 + r, col = nt * 16 + l15;
        *(ushort*)((char*)Pw + pswz(row, col * 2)) = f2b(p[nt][r]);
      }
    __asm__ volatile("s_waitcnt lgkmcnt(0)" ::: "memory");
    short8 pa = *(const short8*)((const char*)Pw + pswz(l15, hi * 16));

    // O += P @ H (keys half*32 .. half*32+31)
    __builtin_amdgcn_s_setprio(1);
#pragma unroll
    for (int dt = 0; dt < 16; ++dt) {
      int dcol = dt * 16 + l15;
      short8 hf = *(const short8*)((const char*)Ht +
          ((dcol * 128 + (half * 32 + hi * 8) * 2) ^ ((dcol & 7) << 4)));
      o[dt] = __builtin_amdgcn_mfma_f32_16x16x32_bf16(pa, hf, o[dt], 0, 0, 0);
    }
    __builtin_amdgcn_s_setprio(0);

    if (t < 15) {
      // ballot next tile's mask into the other parity
#pragma unroll
      for (int j = 0; j < 8; ++j) {
        unsigned long long mm = __ballot(greg[j] != 0);
        if (lane == 0) {
          M2n[(w * 8 + j) * 2] = (uint)mm;
          M2n[(w * 8 + j) * 2 + 1] = (uint)(mm >> 32);
        }
      }
      // land the staged registers (loads completed during compute)
      STAGE_WRITE(cur ^ 1);
    }

    __syncthreads();  // single barrier per tile
  }

  // ---- reduce row sums once (16-lane groups share a row set) ----
#pragma unroll
  for (int r = 0; r < 4; ++r) {
    lR[r] += __shfl_xor(lR[r], 1);
    lR[r] += __shfl_xor(lR[r], 2);
    lR[r] += __shfl_xor(lR[r], 4);
    lR[r] += __shfl_xor(lR[r], 8);
  }

  // ---- combine wave pairs, epilogue ----
  float* Ob = (float*)smem;  // 4 pairs x [16][256] fp32 = 64 KB (KT0+KT1)
  if (half == 1) {
#pragma unroll
    for (int dt = 0; dt < 16; ++dt)
#pragma unroll
      for (int r = 0; r < 4; ++r) {
        int row = hi * 4 + r;
        int byte = (row * 1024 + (dt * 16 + l15) * 4) ^ ((row & 15) << 6);
        *(float*)((char*)Ob + wg * 16384 + byte) = o[dt][r];
      }
    if (l15 == 0) {
#pragma unroll
      for (int r = 0; r < 4; ++r)
        Cm[wg * 16 + hi * 4 + r] = lR[r];
    }
  }
  __syncthreads();
  if (half == 0) {
#pragma unroll
    for (int r = 0; r < 4; ++r) {
      int rowl = hi * 4 + r;
      float inv = 1.f / (lR[r] + Cm[wg * 16 + rowl]);
      int orow = b * 1024 + q0 + wg * 16 + rowl;
#pragma unroll
      for (int dt = 0; dt < 16; ++dt) {
        int byte = (rowl * 1024 + (dt * 16 + l15) * 4) ^ ((rowl & 15) << 6);
        float ob = *(const float*)((const char*)Ob + wg * 16384 + byte);
        float v = (o[dt][r] + ob) * inv;
        out[orow * 256 + dt * 16 + l15] = fmaxf(v, 0.f);
      }
    }
  }
#undef STAGE_ISSUE
#undef STAGE_WRITE
}

// ---------------------------------------------------------------------------
extern "C" void kernel_launch(void* const* d_in, const int* in_sizes, int n_in,
                              void* d_out, int out_size, void* d_ws,
                              size_t ws_size, hipStream_t stream) {
  const float* feature = (const float*)d_in[0];
  const int* graph = (const int*)d_in[1];
  const float* W_w = (const float*)d_in[2];
  const float* W_b = (const float*)d_in[3];
  const float* Q_w = (const float*)d_in[4];
  const float* Q_b = (const float*)d_in[5];
  const float* K_w = (const float*)d_in[6];
  const float* K_b = (const float*)d_in[7];
  float* out = (float*)d_out;

  ushort* hT = (ushort*)d_ws;         // [B,D,N] bf16   8 MB
  ushort* q = hT + MTOT * DD;         // [B,N,D] bf16   8 MB
  ushort* k = q + MTOT * DD;          // [B,N,D] bf16   8 MB
  ushort* wbf = k + MTOT * DD;        // [3][256*256] bf16  384 KB

  wconv<<<192, 256, 0, stream>>>(W_w, Q_w, K_w, wbf);
  gemm_fused<<<256, 256, 0, stream>>>(feature, wbf, W_b, Q_b, K_b, hT, q, k);
  attn8<<<256, 512, 0, stream>>>(q, k, hT, graph, out);
}

// Round 28
// 80.848 us; speedup vs baseline: 1.0182x; 1.0182x over previous
//
#include <hip/hip_runtime.h>
#include <hip/hip_bf16.h>
#include <stdint.h>

#define DD 256
#define NB 16
#define NN 1024
#define MTOT (NB * NN)  // 16384

typedef __attribute__((ext_vector_type(8))) short short8;
typedef __attribute__((ext_vector_type(4))) float f32x4;

__device__ __forceinline__ ushort f2b(float f) {
  uint32_t u = __float_as_uint(f);
  return (ushort)((u + 0x7fffu + ((u >> 16) & 1u)) >> 16);
}

// ---------------------------------------------------------------------------
// Preconvert the three 256x256 fp32 weight matrices to bf16 (row-major).
__global__ __launch_bounds__(256) void wconv(const float* __restrict__ W_w,
                                             const float* __restrict__ Q_w,
                                             const float* __restrict__ K_w,
                                             ushort* __restrict__ wbf) {
  int idx4 = blockIdx.x * blockDim.x + threadIdx.x;  // [0, 49152)
  int m = idx4 >> 14;          // matrix index 0..2
  int off = idx4 & 16383;      // float4 index within matrix
  const float* src = (m == 0) ? W_w : (m == 1) ? Q_w : K_w;
  float4 v = ((const float4*)src)[off];
  ushort4 b4;
  b4.x = f2b(v.x); b4.y = f2b(v.y); b4.z = f2b(v.z); b4.w = f2b(v.w);
  ((ushort4*)(wbf + m * 65536))[off] = b4;
}

// Stage a preconverted 256x256 bf16 weight matrix into LDS, XOR-swizzled.
__device__ __forceinline__ void stage_wbf(const ushort* __restrict__ Wb,
                                          ushort* Wl, int tid) {
#pragma unroll
  for (int i = 0; i < 32; ++i) {
    int idx8 = i * 256 + tid;        // uint4 index (8 bf16)
    int row = idx8 >> 5;             // 32 uint4 per 256-elem row
    int col0 = (idx8 & 31) << 3;     // element col
    uint4 v = ((const uint4*)Wb)[idx8];
    int byte = (row * 512 + col0 * 2) ^ ((row & 7) << 4);
    *(uint4*)((char*)Wl + byte) = v;
  }
}

// ---------------------------------------------------------------------------
// Fused h/q/k GEMM. Each block owns 64 rows; h never round-trips HBM.
__global__ __launch_bounds__(256, 1) void gemm_fused(
    const float* __restrict__ feature, const ushort* __restrict__ wbf,
    const float* __restrict__ W_b, const float* __restrict__ Q_b,
    const float* __restrict__ K_b, ushort* __restrict__ hT,
    ushort* __restrict__ q, ushort* __restrict__ k) {
  __shared__ ushort Wl[256 * 256];  // 128 KB; doubles as Tl transpose buffer
  const int tid = threadIdx.x;
  const int w = tid >> 6, lane = tid & 63, l15 = lane & 15, hi = lane >> 4;
  const int m0 = blockIdx.x * 64 + w * 16;
  const int arow = m0 + l15;

  // ---- h = feature @ W_w^T + W_b ----
  stage_wbf(wbf, Wl, tid);
  __syncthreads();

  f32x4 acc[16] = {};
#pragma unroll
  for (int kk = 0; kk < 8; ++kk) {
    const int k0 = kk * 32 + hi * 8;
    const float4* ap = (const float4*)(feature + arow * 256 + k0);
    float4 x = ap[0], y = ap[1];
    short8 a;
    a[0] = (short)f2b(x.x); a[1] = (short)f2b(x.y);
    a[2] = (short)f2b(x.z); a[3] = (short)f2b(x.w);
    a[4] = (short)f2b(y.x); a[5] = (short)f2b(y.y);
    a[6] = (short)f2b(y.z); a[7] = (short)f2b(y.w);
#pragma unroll
    for (int et = 0; et < 16; ++et) {
      int er = et * 16 + l15;
      short8 bf = *(const short8*)((const char*)Wl +
                                   ((er * 512 + k0 * 2) ^ ((er & 7) << 4)));
      acc[et] = __builtin_amdgcn_mfma_f32_16x16x32_bf16(a, bf, acc[et], 0, 0, 0);
    }
  }

  ushort hvals[16][4];
#pragma unroll
  for (int et = 0; et < 16; ++et) {
    float bv = W_b[et * 16 + l15];
#pragma unroll
    for (int r = 0; r < 4; ++r) hvals[et][r] = f2b(acc[et][r] + bv);
  }

  // ---- transpose h into Tl(=Wl) [256][64] ----
  __syncthreads();  // all waves done reading Wl
  ushort* Tl = Wl;
  {
    const int mloc = w * 16 + hi * 4;
#pragma unroll
    for (int et = 0; et < 16; ++et)
#pragma unroll
      for (int r = 0; r < 4; ++r)
        Tl[(et * 16 + l15) * 64 + mloc + r] = hvals[et][r];
  }
  __syncthreads();

  // ---- (a) h A-frags back to registers; (b) hT to global ----
  short8 qa[8];
#pragma unroll
  for (int kk = 0; kk < 8; ++kk) {
    const int k0 = kk * 32 + hi * 8;
#pragma unroll
    for (int j = 0; j < 8; ++j)
      qa[kk][j] = (short)Tl[(k0 + j) * 64 + w * 16 + l15];
  }
  {
    const int bidx = blockIdx.x >> 4;
    const int n0 = (blockIdx.x & 15) * 64;
    ushort* dst = hT + bidx * (256 * 1024) + tid * 1024 + n0;
    const uint4* src = (const uint4*)(Tl + tid * 64);
#pragma unroll
    for (int j = 0; j < 8; ++j) ((uint4*)dst)[j] = src[j];
  }
  __syncthreads();  // Tl reads done before Q_w staging overwrites

  // ---- q = h @ Q_w^T + Q_b ----
  stage_wbf(wbf + 65536, Wl, tid);
  __syncthreads();
#pragma unroll
  for (int et = 0; et < 16; ++et) acc[et] = (f32x4){0.f, 0.f, 0.f, 0.f};
#pragma unroll
  for (int kk = 0; kk < 8; ++kk) {
    const int k0 = kk * 32 + hi * 8;
#pragma unroll
    for (int et = 0; et < 16; ++et) {
      int er = et * 16 + l15;
      short8 bf = *(const short8*)((const char*)Wl +
                                   ((er * 512 + k0 * 2) ^ ((er & 7) << 4)));
      acc[et] = __builtin_amdgcn_mfma_f32_16x16x32_bf16(qa[kk], bf, acc[et], 0, 0, 0);
    }
  }
#pragma unroll
  for (int et = 0; et < 16; ++et) {
    int e = et * 16 + l15;
    float bv = Q_b[e];
#pragma unroll
    for (int r = 0; r < 4; ++r)
      q[(m0 + hi * 4 + r) * 256 + e] = f2b(acc[et][r] + bv);
  }
  __syncthreads();  // q-compute reads of Wl done before K_w staging

  // ---- k = h @ K_w^T + K_b ----
  stage_wbf(wbf + 131072, Wl, tid);
  __syncthreads();
#pragma unroll
  for (int et = 0; et < 16; ++et) acc[et] = (f32x4){0.f, 0.f, 0.f, 0.f};
#pragma unroll
  for (int kk = 0; kk < 8; ++kk) {
    const int k0 = kk * 32 + hi * 8;
#pragma unroll
    for (int et = 0; et < 16; ++et) {
      int er = et * 16 + l15;
      short8 bf = *(const short8*)((const char*)Wl +
                                   ((er * 512 + k0 * 2) ^ ((er & 7) << 4)));
      acc[et] = __builtin_amdgcn_mfma_f32_16x16x32_bf16(qa[kk], bf, acc[et], 0, 0, 0);
    }
  }
#pragma unroll
  for (int et = 0; et < 16; ++et) {
    int e = et * 16 + l15;
    float bv = K_b[e];
#pragma unroll
    for (int r = 0; r < 4; ++r)
      k[(m0 + hi * 4 + r) * 256 + e] = f2b(acc[et][r] + bv);
  }
}

// ---------------------------------------------------------------------------
// Fused attention (session best): 8 waves, wave-pair key split, fixed-max
// softmax (|e|<=~0.6 for this problem, exp overflow at 88 -> no online max),
// in-loop graph->bitmask pack (double-buffered M2), double-buffered K/HT
// staging with ONE barrier per tile, pair-combine epilogue through LDS.
#define SM_KT0 0       // ushort [64*256]  32768 B
#define SM_KT1 32768   // ushort [64*256]  32768 B
#define SM_HT0 65536   // ushort [256*64]  32768 B
#define SM_HT1 98304   // ushort [256*64]  32768 B
#define SM_PL 131072   // ushort Pl[8*16*32]  8192 B
#define SM_M2 139264   // uint   M2[2][128]   1024 B
#define SM_CM 140288   // float  Cm[64]        256 B
#define SM_SZ 140544

// P-buffer swizzle: XOR in bits>=4 keeps 16B blocks intact for ds_read_b128.
__device__ __forceinline__ int pswz(int row, int bytecol) {
  return (row * 64 + bytecol) ^ ((row & 7) << 4) ^ ((row >> 3) << 5);
}

__global__ __launch_bounds__(512, 2) void attn8(
    const ushort* __restrict__ Q, const ushort* __restrict__ Kb,
    const ushort* __restrict__ HT, const int* __restrict__ graph,
    float* __restrict__ out) {
  __shared__ __align__(16) char smem[SM_SZ];
  ushort* Pl = (ushort*)(smem + SM_PL);
  uint* M2 = (uint*)(smem + SM_M2);
  float* Cm = (float*)(smem + SM_CM);

  const int tid = threadIdx.x;
  const int w = tid >> 6, lane = tid & 63, l15 = lane & 15, hi = lane >> 4;
  const int wg = w >> 1, half = w & 1;
  // XCD-aware remap: XCD x handles batches {2x, 2x+1}
  const int hw = blockIdx.x;
  const int slot = hw >> 3;
  const int b = (hw & 7) * 2 + (slot >> 4);
  const int q0 = (slot & 15) * 64;
  const int qrow_a = q0 + wg * 16 + l15;
  const int qrow_cl = wg * 16 + hi * 4;  // local row base (+r)
  const int* grow_base = graph + (b * 1024 + q0 + w * 8) * 1024 + lane;

  int greg[8];

#define STAGE_TILE(tt, bb)                                                    \
  {                                                                           \
    ushort* Kd = (ushort*)(smem + ((bb) ? SM_KT1 : SM_KT0));                  \
    ushort* Hd = (ushort*)(smem + ((bb) ? SM_HT1 : SM_HT0));                  \
    _Pragma("unroll") for (int i = 0; i < 4; ++i) {                           \
      int c = i * 512 + tid;                                                  \
      int krow = c >> 5, col0 = (c & 31) << 3;                                \
      uint4 v =                                                               \
          *(const uint4*)(Kb + (b * 1024 + (tt) * 64 + krow) * 256 + col0);   \
      *(uint4*)((char*)Kd + ((krow * 512 + col0 * 2) ^ ((krow & 7) << 4))) =  \
          v;                                                                  \
    }                                                                         \
    _Pragma("unroll") for (int i = 0; i < 4; ++i) {                           \
      int c = i * 512 + tid;                                                  \
      int drow = c >> 3, col0 = (c & 7) << 3;                                 \
      uint4 v = *(const uint4*)(HT + b * (256 * 1024) + drow * 1024 +         \
                                (tt) * 64 + col0);                            \
      *(uint4*)((char*)Hd + ((drow * 128 + col0 * 2) ^ ((drow & 7) << 4))) =  \
          v;                                                                  \
    }                                                                         \
  }

  // ---- prologue: stage tile 0 into buf0; graph(0) ballot into M2[0] ----
#pragma unroll
  for (int j = 0; j < 8; ++j) greg[j] = grow_base[j * 1024];

  STAGE_TILE(0, 0);

  short8 qf[8];
#pragma unroll
  for (int kk = 0; kk < 8; ++kk)
    qf[kk] = *(const short8*)(Q + (b * 1024 + qrow_a) * 256 + kk * 32 + hi * 8);

#pragma unroll
  for (int j = 0; j < 8; ++j) {
    unsigned long long mm = __ballot(greg[j] != 0);
    if (lane == 0) {
      M2[(w * 8 + j) * 2] = (uint)mm;
      M2[(w * 8 + j) * 2 + 1] = (uint)(mm >> 32);
    }
  }

  float lR[4] = {0.f, 0.f, 0.f, 0.f};  // per-LANE partial row sums
  f32x4 o[16] = {};

  __syncthreads();  // tile 0 staged

  for (int t = 0; t < 16; ++t) {
    const int cur = t & 1;
    const ushort* Kt = (const ushort*)(smem + (cur ? SM_KT1 : SM_KT0));
    const ushort* Ht = (const ushort*)(smem + (cur ? SM_HT1 : SM_HT0));
    const uint* M2c = M2 + cur * 128;
    uint* M2n = M2 + (cur ^ 1) * 128;

    // issue next tile's graph loads NOW; compute covers the HBM latency
    if (t < 15) {
#pragma unroll
      for (int j = 0; j < 8; ++j) greg[j] = grow_base[j * 1024 + (t + 1) * 64];
    }

    // S = q @ k^T : 16 rows x 32 keys (this wave's half)
    f32x4 s[2] = {};
    __builtin_amdgcn_s_setprio(1);
#pragma unroll
    for (int kk = 0; kk < 8; ++kk) {
#pragma unroll
      for (int nt = 0; nt < 2; ++nt) {
        int krow = half * 32 + nt * 16 + l15;
        short8 kf = *(const short8*)((const char*)Kt +
            ((krow * 512 + (kk * 32 + hi * 8) * 2) ^ ((krow & 7) << 4)));
        s[nt] = __builtin_amdgcn_mfma_f32_16x16x32_bf16(qf[kk], kf, s[nt], 0, 0, 0);
      }
    }
    __builtin_amdgcn_s_setprio(0);

    // scale, leaky, mask, exp — per-lane VALU only
    float p[2][4];
#pragma unroll
    for (int r = 0; r < 4; ++r) {
      uint mw = M2c[(qrow_cl + r) * 2 + half];
      float v0 = s[0][r] * 0.0625f; v0 = (v0 >= 0.f) ? v0 : 0.2f * v0;
      float v1 = s[1][r] * 0.0625f; v1 = (v1 >= 0.f) ? v1 : 0.2f * v1;
      float p0 = ((mw >> l15) & 1u) ? __expf(v0) : 0.f;
      float p1 = ((mw >> (16 + l15)) & 1u) ? __expf(v1) : 0.f;
      p[0][r] = p0; p[1][r] = p1;
      lR[r] += p0 + p1;
    }

    // P (C-layout) -> per-wave LDS -> A-frag layout
    ushort* Pw = Pl + w * 512;
#pragma unroll
    for (int nt = 0; nt < 2; ++nt)
#pragma unroll
      for (int r = 0; r < 4; ++r) {
        int row = hi * 4 + r, col = nt * 16 + l15;
        *(ushort*)((char*)Pw + pswz(row, col * 2)) = f2b(p[nt][r]);
      }
    __asm__ volatile("s_waitcnt lgkmcnt(0)" ::: "memory");
    short8 pa = *(const short8*)((const char*)Pw + pswz(l15, hi * 16));

    // O += P @ H (keys half*32 .. half*32+31)
    __builtin_amdgcn_s_setprio(1);
#pragma unroll
    for (int dt = 0; dt < 16; ++dt) {
      int dcol = dt * 16 + l15;
      short8 hf = *(const short8*)((const char*)Ht +
          ((dcol * 128 + (half * 32 + hi * 8) * 2) ^ ((dcol & 7) << 4)));
      o[dt] = __builtin_amdgcn_mfma_f32_16x16x32_bf16(pa, hf, o[dt], 0, 0, 0);
    }
    __builtin_amdgcn_s_setprio(0);

    if (t < 15) {
      // ballot next tile's mask into the other parity
#pragma unroll
      for (int j = 0; j < 8; ++j) {
        unsigned long long mm = __ballot(greg[j] != 0);
        if (lane == 0) {
          M2n[(w * 8 + j) * 2] = (uint)mm;
          M2n[(w * 8 + j) * 2 + 1] = (uint)(mm >> 32);
        }
      }
      // stage next tile into the other buffer
      STAGE_TILE(t + 1, cur ^ 1);
    }

    __syncthreads();  // single barrier per tile
  }

  // ---- reduce row sums once (16-lane groups share a row set) ----
#pragma unroll
  for (int r = 0; r < 4; ++r) {
    lR[r] += __shfl_xor(lR[r], 1);
    lR[r] += __shfl_xor(lR[r], 2);
    lR[r] += __shfl_xor(lR[r], 4);
    lR[r] += __shfl_xor(lR[r], 8);
  }

  // ---- combine wave pairs, epilogue ----
  float* Ob = (float*)smem;  // 4 pairs x [16][256] fp32 = 64 KB (KT0+KT1)
  if (half == 1) {
#pragma unroll
    for (int dt = 0; dt < 16; ++dt)
#pragma unroll
      for (int r = 0; r < 4; ++r) {
        int row = hi * 4 + r;
        int byte = (row * 1024 + (dt * 16 + l15) * 4) ^ ((row & 15) << 6);
        *(float*)((char*)Ob + wg * 16384 + byte) = o[dt][r];
      }
    if (l15 == 0) {
#pragma unroll
      for (int r = 0; r < 4; ++r)
        Cm[wg * 16 + hi * 4 + r] = lR[r];
    }
  }
  __syncthreads();
  if (half == 0) {
#pragma unroll
    for (int r = 0; r < 4; ++r) {
      int rowl = hi * 4 + r;
      float inv = 1.f / (lR[r] + Cm[wg * 16 + rowl]);
      int orow = b * 1024 + q0 + wg * 16 + rowl;
#pragma unroll
      for (int dt = 0; dt < 16; ++dt) {
        int byte = (rowl * 1024 + (dt * 16 + l15) * 4) ^ ((rowl & 15) << 6);
        float ob = *(const float*)((const char*)Ob + wg * 16384 + byte);
        float v = (o[dt][r] + ob) * inv;
        out[orow * 256 + dt * 16 + l15] = fmaxf(v, 0.f);
      }
    }
  }
#undef STAGE_TILE
}

// ---------------------------------------------------------------------------
extern "C" void kernel_launch(void* const* d_in, const int* in_sizes, int n_in,
                              void* d_out, int out_size, void* d_ws,
                              size_t ws_size, hipStream_t stream) {
  const float* feature = (const float*)d_in[0];
  const int* graph = (const int*)d_in[1];
  const float* W_w = (const float*)d_in[2];
  const float* W_b = (const float*)d_in[3];
  const float* Q_w = (const float*)d_in[4];
  const float* Q_b = (const float*)d_in[5];
  const float* K_w = (const float*)d_in[6];
  const float* K_b = (const float*)d_in[7];
  float* out = (float*)d_out;

  ushort* hT = (ushort*)d_ws;         // [B,D,N] bf16   8 MB
  ushort* q = hT + MTOT * DD;         // [B,N,D] bf16   8 MB
  ushort* k = q + MTOT * DD;          // [B,N,D] bf16   8 MB
  ushort* wbf = k + MTOT * DD;        // [3][256*256] bf16  384 KB

  wconv<<<192, 256, 0, stream>>>(W_w, Q_w, K_w, wbf);
  gemm_fused<<<256, 256, 0, stream>>>(feature, wbf, W_b, Q_b, K_b, hT, q, k);
  attn8<<<256, 512, 0, stream>>>(q, k, hT, graph, out);
}